// Round 7
// baseline (6282.544 us; speedup 1.0000x reference)
//
#include <hip/hip_runtime.h>

#define B_   16
#define T_   1600
#define D_   512
#define U_   1024
#define G_   4096           // 4*U
#define NWG  256            // 128 per direction, 1 per CU
#define TPB  256
#define KTOT 1536           // D + U
#define APAD 1544           // weight staging pad (ushort elems)
#define ROWB (APAD*2)

typedef __attribute__((ext_vector_type(8))) __bf16 bf16x8;
typedef __attribute__((ext_vector_type(4))) float  f32x4;
typedef __attribute__((ext_vector_type(2))) float  f32x2;
typedef __attribute__((ext_vector_type(8))) unsigned short us8v;
typedef unsigned long long u64;

__device__ __forceinline__ unsigned short f2bf(float f) {
  unsigned u = __builtin_bit_cast(unsigned, f);
  u += 0x7FFFu + ((u >> 16) & 1u);
  return (unsigned short)(u >> 16);
}
__device__ __forceinline__ bf16x8 cvt8(const float4 a, const float4 b) {
  us8v r;
  r[0]=f2bf(a.x); r[1]=f2bf(a.y); r[2]=f2bf(a.z); r[3]=f2bf(a.w);
  r[4]=f2bf(b.x); r[5]=f2bf(b.y); r[6]=f2bf(b.z); r[7]=f2bf(b.w);
  return __builtin_bit_cast(bf16x8, r);
}
__device__ __forceinline__ float sigm(float x){ return 1.f / (1.f + __expf(-x)); }
__device__ __forceinline__ float tanh_(float x){ return 1.f - 2.f / (__expf(2.f*x) + 1.f); }

extern "C" __global__ void __launch_bounds__(TPB, 1)
bilstm_kernel(const float* __restrict__ x, const int* __restrict__ xlen,
              const float* __restrict__ kf, const float* __restrict__ rkf, const float* __restrict__ bf_,
              const float* __restrict__ kb, const float* __restrict__ rkb, const float* __restrict__ bb_,
              float* __restrict__ out, unsigned* __restrict__ flags,
              unsigned short* __restrict__ hbuf)
{
  extern __shared__ char smem[];

  const int tid = threadIdx.x;
  const int wg  = blockIdx.x;
  const int dir = wg >> 7;
  const int slot = wg & 127;
  const int u0  = slot << 3;

  if (wg == 0 && tid < B_)
    out[(size_t)B_*T_*2*U_ + tid] = (float)xlen[tid];

  const float* Km = dir ? kb  : kf;
  const float* Rm = dir ? rkb : rkf;
  const float* Bv = dir ? bb_ : bf_;

  const int w = tid >> 6, l = tid & 63;
  const int ntile = w & 1, khalf = w >> 1;

  // ---- phase 1: stage weight slice [1536][32] -> LDS bf16 (coalesced) ----
  {
    char* Wb = smem;
    for (int i = tid; i < KTOT*32; i += TPB) {
      int k = i >> 5, c = i & 31;
      int gc = ((c >> 3) << 10) + u0 + (c & 7);
      float wv = (k < D_) ? Km[(size_t)k*G_ + gc] : Rm[(size_t)(k-D_)*G_ + gc];
      *(unsigned short*)(Wb + c*ROWB + (k << 1)) = f2bf(wv);
    }
  }
  __syncthreads();

  // ---- phase 2: each thread pulls its 24 B-fragments into VGPRs ----
  bf16x8 wx[8], wh[16];
  {
    const char* Brow = smem + (ntile*16 + (l & 15))*ROWB + ((l >> 4) << 4);
    #pragma unroll
    for (int i = 0; i < 8; ++i)  wx[i] = *(const bf16x8*)(Brow + ((khalf*8 + i) << 6));
    #pragma unroll
    for (int i = 0; i < 16; ++i) wh[i] = *(const bf16x8*)(Brow + ((16 + khalf*16 + i) << 6));
  }
  __syncthreads();   // weight LDS dead; reuse: gates @0 (4KB), h-stage @4096 (32KB)

  float* gates = (float*)smem;            // [2 khalf][16 b][32 col]
  char*  hst   = smem + 4096;             // [16 b][2048 B] XOR-swizzled bf16 h
  float* gp    = gates + khalf*512;
  const int drow0 = (l >> 4) << 2, dcol = ntile*16 + (l & 15);

  // epilogue-thread state (wave 0): 2 units each, bias + cell in registers
  const int eb = tid >> 2, eup = (tid & 3) << 1;
  float bi0=0, bi1=0, bff0=0, bff1=0, bz0=0, bz1=0, bo0=0, bo1=0, c0=0, c1=0;
  if (tid < 64) {
    bi0 = Bv[u0+eup];        bi1 = Bv[u0+eup+1];
    bff0= Bv[1024+u0+eup];   bff1= Bv[1024+u0+eup+1];
    bz0 = Bv[2048+u0+eup];   bz1 = Bv[2048+u0+eup+1];
    bo0 = Bv[3072+u0+eup];   bo1 = Bv[3072+u0+eup+1];
  }

  unsigned* myflags = flags + dir*128;

  const float* xbase = x + (size_t)(l & 15)*T_*D_ + khalf*256 + ((l >> 4) << 3);

  // A-frag LDS read base: row = l&15, k-byte base; swizzle XOR (row&7)<<4
  const char* hrow  = hst + (l & 15)*2048;
  const int   kbase = (khalf*512 + ((l >> 4) << 3)) << 1;
  const int   swz   = ((l & 15) & 7) << 4;

  // h-stage decomposition for the coop load (slot-major hbuf layout)
  const int st_b    = (tid >> 1) & 15;                 // batch row this thread writes
  const int st_base = ((tid >> 5) << 4) + ((tid & 1) << 3);  // slot-within-j*16 + half
  char* st_dst = hst + st_b*2048;
  const int st_swz = (st_b & 7) << 4;

  // prologue: x-projection for t=0
  f32x4 acc = {0.f, 0.f, 0.f, 0.f};
  {
    const float* xA = xbase + (size_t)(dir ? (T_ - 1) : 0) * D_;
    #pragma unroll
    for (int i = 0; i < 8; ++i) {
      float4 lo = *(const float4*)(xA + i*32);
      float4 hi = *(const float4*)(xA + i*32 + 4);
      acc = __builtin_amdgcn_mfma_f32_16x16x32_bf16(cvt8(lo, hi), wx[i], acc, 0, 0, 0);
    }
  }

  for (int t = 0; t < T_; ++t) {
    const int tg = dir ? (T_ - 1 - t) : t;

    if (t > 0) {
      // wave 1 polls (overlaps wave 0's previous epilogue + flag publish)
      if (tid >= 64 && tid < 128) {
        const unsigned tgt = (unsigned)t;
        long long guard = 0;
        for (;;) {
          unsigned a = __hip_atomic_load(myflags + l,      __ATOMIC_RELAXED, __HIP_MEMORY_SCOPE_AGENT);
          unsigned b = __hip_atomic_load(myflags + 64 + l, __ATOMIC_RELAXED, __HIP_MEMORY_SCOPE_AGENT);
          if (__all((a >= tgt) && (b >= tgt))) break;
          __builtin_amdgcn_s_sleep(1);
          if (++guard > (1LL << 22)) break;
        }
      }
      __syncthreads();   // S1: handoff confirmed; prev gates reads done

      // cooperative coalesced h load -> LDS (slot-major src, swizzled dst)
      {
        const u64* hsrc = (const u64*)(hbuf + (((size_t)((t & 1)*2 + dir)) << 14));
        u64 tmp[16];
        #pragma unroll
        for (int j = 0; j < 16; ++j)
          tmp[j] = __hip_atomic_load(hsrc + tid + j*256, __ATOMIC_RELAXED, __HIP_MEMORY_SCOPE_AGENT);
        #pragma unroll
        for (int j = 0; j < 16; ++j)
          *(u64*)(st_dst + ((j*128 + st_base) ^ st_swz)) = tmp[j];
      }
      __syncthreads();   // S2: h-stage complete

      // recurrent MFMAs from LDS; 2 accumulators break the dep chain
      f32x4 acc2 = {0.f, 0.f, 0.f, 0.f};
      #pragma unroll
      for (int i = 0; i < 16; i += 2) {
        bf16x8 a0 = *(const bf16x8*)(hrow + ((kbase + i*64)     ^ swz));
        bf16x8 a1 = *(const bf16x8*)(hrow + ((kbase + (i+1)*64) ^ swz));
        acc  = __builtin_amdgcn_mfma_f32_16x16x32_bf16(a0, wh[i],   acc,  0, 0, 0);
        acc2 = __builtin_amdgcn_mfma_f32_16x16x32_bf16(a1, wh[i+1], acc2, 0, 0, 0);
      }
      acc[0]+=acc2[0]; acc[1]+=acc2[1]; acc[2]+=acc2[2]; acc[3]+=acc2[3];
    }

    #pragma unroll
    for (int j = 0; j < 4; ++j) gp[(drow0 + j)*32 + dcol] = acc[j];
    __syncthreads();   // S3: gates ready; h-stage reads done

    // epilogue: wave 0. Order: h-store -> drain -> flag -> out-store (off-path)
    if (tid < 64) {
      const float* g0 = gates + eb*32 + eup;
      float gi0 = g0[0]  + g0[512] + bi0,  gi1 = g0[1]  + g0[513] + bi1;
      float gf0 = g0[8]  + g0[520] + bff0, gf1 = g0[9]  + g0[521] + bff1;
      float gz0 = g0[16] + g0[528] + bz0,  gz1 = g0[17] + g0[529] + bz1;
      float go0 = g0[24] + g0[536] + bo0,  go1 = g0[25] + g0[537] + bo1;
      c0 = sigm(gf0)*c0 + sigm(gi0)*tanh_(gz0);
      c1 = sigm(gf1)*c1 + sigm(gi1)*tanh_(gz1);
      float h0 = sigm(go0)*tanh_(c0);
      float h1 = sigm(go1)*tanh_(c1);
      // h publish: slot-major [slot][b][8u] -> one 256B burst per producer
      unsigned hp = ((unsigned)f2bf(h1) << 16) | (unsigned)f2bf(h0);
      unsigned* hdst = (unsigned*)(hbuf + (((size_t)(((t & 1) ^ 1)*2 + dir)) << 14)
                                   + (slot << 7) + (eb << 3) + eup);
      __hip_atomic_store(hdst, hp, __ATOMIC_RELAXED, __HIP_MEMORY_SCOPE_AGENT);
      asm volatile("s_waitcnt vmcnt(0)" ::: "memory");   // h at LLC before flag
      if (tid == 0)
        __hip_atomic_store(myflags + slot, (unsigned)(t + 1), __ATOMIC_RELAXED, __HIP_MEMORY_SCOPE_AGENT);
      // out store AFTER flag, cached (acks at LLC during next step)
      f32x2 ho; ho.x = h0; ho.y = h1;
      *(f32x2*)(out + ((size_t)eb*T_ + tg)*(2*U_) + (dir << 10) + u0 + eup) = ho;
    }

    if (t + 1 < T_) {
      // x-projection for t+1 in the flag-propagation shadow (all waves)
      const float* xA = xbase + (size_t)(dir ? (T_ - 2 - t) : (t + 1)) * D_;
      f32x4 nacc = {0.f, 0.f, 0.f, 0.f};
      #pragma unroll
      for (int i = 0; i < 8; ++i) {
        float4 lo = *(const float4*)(xA + i*32);
        float4 hi = *(const float4*)(xA + i*32 + 4);
        nacc = __builtin_amdgcn_mfma_f32_16x16x32_bf16(cvt8(lo, hi), wx[i], nacc, 0, 0, 0);
      }
      acc = nacc;
    }
  }
}

extern "C" void kernel_launch(void* const* d_in, const int* in_sizes, int n_in,
                              void* d_out, int out_size, void* d_ws, size_t ws_size,
                              hipStream_t stream) {
  const float* x   = (const float*)d_in[0];
  const int*   xl  = (const int*)d_in[1];
  const float* kf  = (const float*)d_in[2];
  const float* rkf = (const float*)d_in[3];
  const float* bf_ = (const float*)d_in[4];
  const float* kb  = (const float*)d_in[5];
  const float* rkb = (const float*)d_in[6];
  const float* bb_ = (const float*)d_in[7];
  float* out = (float*)d_out;

  unsigned* flags = (unsigned*)d_ws;                              // 2 x 128 u32
  unsigned short* hbuf = (unsigned short*)((char*)d_ws + 1024);   // 4 x 32 KB, slot-major

  (void)hipMemsetAsync(d_ws, 0, 1024, stream);    // reset flags every launch (graph-safe)

  const size_t smem = 32*(size_t)ROWB;   // 98,816 B (weight staging); runtime uses 36,864 B
  bilstm_kernel<<<NWG, TPB, smem, stream>>>(x, xl, kf, rkf, bf_, kb, rkb, bb_, out, flags, hbuf);
}